// Round 3
// baseline (2325.390 us; speedup 1.0000x reference)
//
#include <hip/hip_runtime.h>

#define DEV __device__ __forceinline__

typedef __attribute__((ext_vector_type(8))) short short8;
typedef __attribute__((ext_vector_type(8))) __bf16 bf16x8;
typedef __attribute__((ext_vector_type(4))) float f32x4;

// ---------- constants for this problem ----------
// N=32, T=1024, D=1152, H=16, DH=72, MLP=4608
#define TD      1024
#define DD      1152
#define HH      16
#define DHH     72
#define MLPD    4608
#define QKVN    3456
#define ADAN    6912
#define MROWS   32768      // 32*1024

DEV unsigned short f32_to_bf16(float f) {
  unsigned int u = __float_as_uint(f);
  u += 0x7fffu + ((u >> 16) & 1u);
  return (unsigned short)(u >> 16);
}

DEV void gl16(const void* g, void* l) {
  __builtin_amdgcn_global_load_lds((__attribute__((address_space(1))) void*)g,
                                   (__attribute__((address_space(3))) void*)l,
                                   16, 0, 0);
}

DEV bf16x8 zero_bf16x8() {
  short8 z = {0, 0, 0, 0, 0, 0, 0, 0};
  return __builtin_bit_cast(bf16x8, z);
}

DEV float gelu_exact(float v) {
  return 0.5f * v * (1.0f + erff(v * 0.70710678118654752f));
}

#define WAITV(n) asm volatile("s_waitcnt vmcnt(" #n ")" ::: "memory")
#define BAR()                                  \
  do {                                         \
    __builtin_amdgcn_s_barrier();              \
    __builtin_amdgcn_sched_barrier(0);         \
  } while (0)

// ---------------- weight transpose: fp32 W[K][N] -> bf16 Wt[N][K] ----------------
__global__ __launch_bounds__(256) void wtrans_kernel(const float* __restrict__ W,
                                                     unsigned short* __restrict__ Wt,
                                                     int K, int N) {
  __shared__ unsigned short tile[32][33];
  const int nb = blockIdx.x * 32, kb = blockIdx.y * 32;
  const int tx = threadIdx.x, ty = threadIdx.y;  // block (32,8)
  #pragma unroll
  for (int i = ty; i < 32; i += 8)
    tile[i][tx] = f32_to_bf16(W[(size_t)(kb + i) * N + nb + tx]);
  __syncthreads();
  #pragma unroll
  for (int i = ty; i < 32; i += 8)
    Wt[(size_t)(nb + i) * K + kb + tx] = tile[tx][i];
}

// ---------------- ada = silu(c) @ ada_w + ada_b  (fp32) ----------------
__global__ __launch_bounds__(256) void ada_kernel(const float* __restrict__ c,
                                                  const float* __restrict__ ada_w,
                                                  const float* __restrict__ ada_b,
                                                  float* __restrict__ ada_out) {
  __shared__ float sc[DD];
  const int n = blockIdx.y;
  const int col = blockIdx.x * 256 + threadIdx.x;
  for (int i = threadIdx.x; i < DD; i += 256) {
    float v = c[(size_t)n * DD + i];
    sc[i] = v / (1.0f + __expf(-v));
  }
  __syncthreads();
  float acc = ada_b[col];
  #pragma unroll 8
  for (int k = 0; k < DD; ++k)
    acc += sc[k] * ada_w[(size_t)k * ADAN + col];
  ada_out[(size_t)n * ADAN + col] = acc;
}

// ---------------- LayerNorm + modulate -> bf16 ----------------
__global__ __launch_bounds__(256) void ln_mod_kernel(const float* __restrict__ X,
                                                     const float* __restrict__ ada,
                                                     int soff,
                                                     unsigned short* __restrict__ out) {
  const int row = blockIdx.x;       // 0..32767
  const int batch = row >> 10;
  const float* xr = X + (size_t)row * DD;
  const int t = threadIdx.x;

  float4 v0 = reinterpret_cast<const float4*>(xr)[t];
  float4 v1 = make_float4(0.f, 0.f, 0.f, 0.f);
  const bool has2 = (t < 32);
  if (has2) v1 = reinterpret_cast<const float4*>(xr)[256 + t];

  float s  = v0.x + v0.y + v0.z + v0.w + v1.x + v1.y + v1.z + v1.w;
  float sq = v0.x*v0.x + v0.y*v0.y + v0.z*v0.z + v0.w*v0.w
           + v1.x*v1.x + v1.y*v1.y + v1.z*v1.z + v1.w*v1.w;
  #pragma unroll
  for (int m = 1; m < 64; m <<= 1) {
    s  += __shfl_xor(s, m);
    sq += __shfl_xor(sq, m);
  }
  __shared__ float red[8];
  const int wv = t >> 6;
  if ((t & 63) == 0) { red[wv] = s; red[4 + wv] = sq; }
  __syncthreads();
  s  = red[0] + red[1] + red[2] + red[3];
  sq = red[4] + red[5] + red[6] + red[7];
  const float mean = s * (1.0f / 1152.0f);
  const float var  = sq * (1.0f / 1152.0f) - mean * mean;
  const float rstd = rsqrtf(var + 1e-6f);

  const float* shp = ada + (size_t)batch * ADAN + soff;
  const float* scp = shp + DD;
  unsigned short* orow = out + (size_t)row * DD;

  {
    const int col = t * 4;
    ushort4 o4;
    o4.x = f32_to_bf16((v0.x - mean) * rstd * (1.0f + scp[col + 0]) + shp[col + 0]);
    o4.y = f32_to_bf16((v0.y - mean) * rstd * (1.0f + scp[col + 1]) + shp[col + 1]);
    o4.z = f32_to_bf16((v0.z - mean) * rstd * (1.0f + scp[col + 2]) + shp[col + 2]);
    o4.w = f32_to_bf16((v0.w - mean) * rstd * (1.0f + scp[col + 3]) + shp[col + 3]);
    reinterpret_cast<ushort4*>(orow)[t] = o4;
  }
  if (has2) {
    const int col = 1024 + t * 4;
    ushort4 o4;
    o4.x = f32_to_bf16((v1.x - mean) * rstd * (1.0f + scp[col + 0]) + shp[col + 0]);
    o4.y = f32_to_bf16((v1.y - mean) * rstd * (1.0f + scp[col + 1]) + shp[col + 1]);
    o4.z = f32_to_bf16((v1.z - mean) * rstd * (1.0f + scp[col + 2]) + shp[col + 2]);
    o4.w = f32_to_bf16((v1.w - mean) * rstd * (1.0f + scp[col + 3]) + shp[col + 3]);
    reinterpret_cast<ushort4*>(orow)[256 + t] = o4;
  }
}

// ---------------- GEMM: C[M][N] = A[M][K](bf16) * Bt[N][K](bf16)^T + epilogue ----------------
// BM=256, BN=128, BK=32; 4 waves, wave-tile 128x64; 4-phase K-step with counted vmcnt.
// LDS slot permutation (conflict-free ds_read, linear gl16 dest):
//   16B-slot(row,c16) = (row>>3)*32 + c16*8 + (row&7); write side pre-permutes GLOBAL src.
// EPI: 0 = +bias -> bf16 (qkv); 1 = resid + gate*(+bias) -> f32; 2 = gelu(+bias) -> bf16;
//      3 = out += gate*(+bias) -> f32 in-place.
template <int EPI>
__global__ __launch_bounds__(256, 2) void gemm256(
    const unsigned short* __restrict__ A, const unsigned short* __restrict__ Bt,
    const float* __restrict__ bias, const float* __restrict__ ada, int ada_off,
    const float* __restrict__ resid, unsigned short* __restrict__ out_bf,
    float* __restrict__ out_f, int N, int K, int nbn) {
  __shared__ unsigned short lds[2][12288];  // [buf][ A 256x32 (8192) | B 128x32 (4096) ]
  const int tid = threadIdx.x;
  const int lane = tid & 63, w = tid >> 6;
  const int wm = w >> 1, wn = w & 1;
  const int l15 = lane & 15, lg = lane >> 4;

  // T1: bijective XCD-chunk swizzle (nwg = 128*nbn, always %8==0), GM=8 panels
  const int bid = blockIdx.x;
  const int xcd = bid & 7, idx = bid >> 3;       // idx < 16*nbn
  const int panel = idx / (nbn * 8);             // 0..1
  const int rr = idx % (nbn * 8);
  const int bn = rr >> 3;
  const int bm = xcd * 16 + panel * 8 + (rr & 7);

  const unsigned short* __restrict__ Ag = A + (size_t)bm * 256 * K;
  const unsigned short* __restrict__ Bg = Bt + (size_t)bn * 128 * K;

  // staging decode: chunk-local byte gb -> (row, c16) under the slot permutation
  int srow[4], sc16[4];
  #pragma unroll
  for (int i = 0; i < 4; ++i) {
    const int gb = i * 4096 + tid * 16;
    srow[i] = ((gb >> 9) << 3) | ((gb >> 4) & 7);
    sc16[i] = (gb >> 7) & 3;
  }

  // ds_read bases (shorts): slot(row,c16)*8 with row = {wm*128|wn*64} + frag*16 + l15, c16 = lg
  const int abase = wm * 4096 + ((l15 >> 3) << 8) + (lg << 6) + ((l15 & 7) << 3);
  const int bbase = 8192 + wn * 2048 + ((l15 >> 3) << 8) + (lg << 6) + ((l15 & 7) << 3);

  f32x4 acc[8][4];
  #pragma unroll
  for (int m = 0; m < 8; ++m)
    #pragma unroll
    for (int nn = 0; nn < 4; ++nn)
      acc[m][nn] = (f32x4){0.f, 0.f, 0.f, 0.f};

  const int NT = K >> 5;

#define STG_A(bf_, kt_, i_) gl16(Ag + (size_t)srow[i_] * K + (kt_) * 32 + sc16[i_] * 8, \
                                 &lds[bf_][(i_) * 2048 + tid * 8])
#define STG_B(bf_, kt_, j_) gl16(Bg + (size_t)srow[j_] * K + (kt_) * 32 + sc16[j_] * 8, \
                                 &lds[bf_][8192 + (j_) * 2048 + tid * 8])

#define MFMA_PAIR(M0, M1)                                                                \
  do {                                                                                   \
    bf16x8 a0_ = *(const bf16x8*)&lb[abase + (M0) * 512];                                \
    bf16x8 a1_ = *(const bf16x8*)&lb[abase + (M1) * 512];                                \
    __builtin_amdgcn_s_setprio(1);                                                       \
    acc[M0][0] = __builtin_amdgcn_mfma_f32_16x16x32_bf16(a0_, bf0, acc[M0][0], 0, 0, 0); \
    acc[M0][1] = __builtin_amdgcn_mfma_f32_16x16x32_bf16(a0_, bf1, acc[M0][1], 0, 0, 0); \
    acc[M0][2] = __builtin_amdgcn_mfma_f32_16x16x32_bf16(a0_, bf2, acc[M0][2], 0, 0, 0); \
    acc[M0][3] = __builtin_amdgcn_mfma_f32_16x16x32_bf16(a0_, bf3, acc[M0][3], 0, 0, 0); \
    acc[M1][0] = __builtin_amdgcn_mfma_f32_16x16x32_bf16(a1_, bf0, acc[M1][0], 0, 0, 0); \
    acc[M1][1] = __builtin_amdgcn_mfma_f32_16x16x32_bf16(a1_, bf1, acc[M1][1], 0, 0, 0); \
    acc[M1][2] = __builtin_amdgcn_mfma_f32_16x16x32_bf16(a1_, bf2, acc[M1][2], 0, 0, 0); \
    acc[M1][3] = __builtin_amdgcn_mfma_f32_16x16x32_bf16(a1_, bf3, acc[M1][3], 0, 0, 0); \
    __builtin_amdgcn_s_setprio(0);                                                       \
  } while (0)

  // prologue: tile 0, issue order = steady-state order [B0 B1][A0 A2][A1 A3]
  STG_B(0, 0, 0); STG_B(0, 0, 1);
  STG_A(0, 0, 0); STG_A(0, 0, 2);
  STG_A(0, 0, 1); STG_A(0, 0, 3);

  for (int kt = 0; kt < NT; ++kt) {
    const int cb = kt & 1, nbuf = cb ^ 1;
    const unsigned short* lb = lds[cb];
    // ---- ph0: validate {B, A02}(kt); prefetch B(kt+1)
    if (kt + 1 < NT) {
      STG_B(nbuf, kt + 1, 0); STG_B(nbuf, kt + 1, 1);
      WAITV(4);
    } else {
      WAITV(2);
    }
    BAR();
    bf16x8 bf0 = *(const bf16x8*)&lb[bbase];
    bf16x8 bf1 = *(const bf16x8*)&lb[bbase + 512];
    bf16x8 bf2 = *(const bf16x8*)&lb[bbase + 1024];
    bf16x8 bf3 = *(const bf16x8*)&lb[bbase + 1536];
    MFMA_PAIR(0, 1);
    // ---- ph1: prefetch A02(kt+1)
    if (kt + 1 < NT) { STG_A(nbuf, kt + 1, 0); STG_A(nbuf, kt + 1, 2); }
    MFMA_PAIR(2, 3);
    // ---- ph2: validate A13(kt); prefetch A13(kt+1)
    if (kt + 1 < NT) {
      STG_A(nbuf, kt + 1, 1); STG_A(nbuf, kt + 1, 3);
      WAITV(6);
    } else {
      WAITV(0);
    }
    BAR();
    MFMA_PAIR(4, 5);
    // ---- ph3
    MFMA_PAIR(6, 7);
  }
#undef STG_A
#undef STG_B
#undef MFMA_PAIR

  // epilogue
  const size_t row0 = (size_t)bm * 256 + wm * 128;
  const int col0 = bn * 128 + wn * 64;
  const int batch = (int)(row0 >> 10);
  #pragma unroll
  for (int nn = 0; nn < 4; ++nn) {
    const int colg = col0 + nn * 16 + l15;
    const float bv = bias[colg];
    float g = 0.0f;
    if constexpr (EPI == 1 || EPI == 3) g = ada[(size_t)batch * ADAN + ada_off + colg];
    #pragma unroll
    for (int mf = 0; mf < 8; ++mf) {
      #pragma unroll
      for (int r = 0; r < 4; ++r) {
        const size_t oidx = (row0 + mf * 16 + lg * 4 + r) * (size_t)N + colg;
        const float v = acc[mf][nn][r] + bv;
        if constexpr (EPI == 0)      out_bf[oidx] = f32_to_bf16(v);
        else if constexpr (EPI == 2) out_bf[oidx] = f32_to_bf16(gelu_exact(v));
        else if constexpr (EPI == 1) out_f[oidx] = resid[oidx] + g * v;
        else                         out_f[oidx] = out_f[oidx] + g * v;
      }
    }
  }
}

// ---------------- per-token head attention ----------------
// attn = softmax_k( sum_d q[n,t,h,d]*scale * k[n,t,kh,d] )  (16x16 per token)
// oh[n,t,h,d] = sum_kh attn[h,kh] * v[n,t,kh,d]
// y flat per batch: index h*73728 + t*72 + d, viewed as [1024][1152]
__global__ __launch_bounds__(256) void attn_kernel(const unsigned short* __restrict__ qkv,
                                                   unsigned short* __restrict__ y) {
  const int tid = threadIdx.x, w = tid >> 6, lane = tid & 63;
  const int l15 = lane & 15, lg = lane >> 4;
  const int tok = blockIdx.x * 4 + w;          // 0..32767
  const int n = tok >> 10, t = tok & 1023;

  __shared__ unsigned short Pl[4][16 * 32];    // per-wave P, K-padded to 32
  __shared__ unsigned short Vl[4][16 * 80];    // per-wave V[kh][d] (stride 80)

  for (int i = lane; i < 16 * 32; i += 64)
    if ((i & 31) >= 16) Pl[w][i] = 0;

  const size_t rowb = (size_t)tok * QKVN;
  const float scale = 0.11785113019775793f;    // 72^-0.5

  bf16x8 aq[3];
  #pragma unroll
  for (int kk = 0; kk < 3; ++kk) {
    const int d0 = kk * 32 + lg * 8;
    aq[kk] = (d0 < DHH) ? *(const bf16x8*)&qkv[rowb + l15 * DHH + d0] : zero_bf16x8();
  }

  for (int c = lane; c < 144; c += 64) {
    const int r = c / 9, cc = (c % 9) * 8;
    *(short8*)&Vl[w][r * 80 + cc] = *(const short8*)&qkv[rowb + 2 * DD + r * DHH + cc];
  }

  f32x4 s = (f32x4){0.f, 0.f, 0.f, 0.f};
  #pragma unroll
  for (int kk = 0; kk < 3; ++kk) {
    const int d0 = kk * 32 + lg * 8;
    bf16x8 bk = (d0 < DHH) ? *(const bf16x8*)&qkv[rowb + DD + l15 * DHH + d0] : zero_bf16x8();
    s = __builtin_amdgcn_mfma_f32_16x16x32_bf16(aq[kk], bk, s, 0, 0, 0);
  }

  float p[4], mx[4], ssum[4];
  #pragma unroll
  for (int r = 0; r < 4; ++r) { p[r] = s[r] * scale; mx[r] = p[r]; }
  #pragma unroll
  for (int mk = 1; mk <= 8; mk <<= 1)
    #pragma unroll
    for (int r = 0; r < 4; ++r) mx[r] = fmaxf(mx[r], __shfl_xor(mx[r], mk));
  #pragma unroll
  for (int r = 0; r < 4; ++r) { p[r] = __expf(p[r] - mx[r]); ssum[r] = p[r]; }
  #pragma unroll
  for (int mk = 1; mk <= 8; mk <<= 1)
    #pragma unroll
    for (int r = 0; r < 4; ++r) ssum[r] += __shfl_xor(ssum[r], mk);

  #pragma unroll
  for (int r = 0; r < 4; ++r)
    Pl[w][(lg * 4 + r) * 32 + l15] = f32_to_bf16(p[r] / ssum[r]);

  bf16x8 pa = *(const bf16x8*)&Pl[w][l15 * 32 + lg * 8];
  const int kb = (lg & 1) * 8;
  f32x4 o[5];
  #pragma unroll
  for (int df = 0; df < 5; ++df) {
    short8 bvv;
    #pragma unroll
    for (int j = 0; j < 8; ++j)
      bvv[j] = (short)Vl[w][(kb + j) * 80 + df * 16 + l15];
    o[df] = __builtin_amdgcn_mfma_f32_16x16x32_bf16(
        pa, __builtin_bit_cast(bf16x8, bvv), (f32x4){0.f, 0.f, 0.f, 0.f}, 0, 0, 0);
  }

  unsigned short* yb = y + (size_t)n * (TD * DD);
  #pragma unroll
  for (int df = 0; df < 5; ++df) {
    const int d = df * 16 + l15;
    if (d < DHH) {
      #pragma unroll
      for (int r = 0; r < 4; ++r) {
        const int h = lg * 4 + r;
        yb[h * 73728 + t * DHH + d] = f32_to_bf16(o[df][r]);
      }
    }
  }
}

// ---------------- host launch ----------------
extern "C" void kernel_launch(void* const* d_in, const int* in_sizes, int n_in,
                              void* d_out, int out_size, void* d_ws, size_t ws_size,
                              hipStream_t stream) {
  (void)in_sizes; (void)n_in; (void)out_size; (void)ws_size;
  const float* x      = (const float*)d_in[0];
  const float* c      = (const float*)d_in[1];
  const float* qkv_w  = (const float*)d_in[2];
  const float* qkv_b  = (const float*)d_in[3];
  const float* proj_w = (const float*)d_in[4];
  const float* proj_b = (const float*)d_in[5];
  const float* fc1_w  = (const float*)d_in[6];
  const float* fc1_b  = (const float*)d_in[7];
  const float* fc2_w  = (const float*)d_in[8];
  const float* fc2_b  = (const float*)d_in[9];
  const float* ada_w  = (const float*)d_in[10];
  const float* ada_b  = (const float*)d_in[11];
  float* out = (float*)d_out;

  char* ws = (char*)d_ws;
  unsigned short* hbuf    = (unsigned short*)ws;
  unsigned short* qkvbuf  = hbuf;
  unsigned short* attnbuf = hbuf + (size_t)MROWS * QKVN;
  size_t off = 301989888ull;
  unsigned short* xm    = (unsigned short*)(ws + off); off += 75497472ull;
  unsigned short* wtq   = (unsigned short*)(ws + off); off += 7962624ull;
  unsigned short* wtp   = (unsigned short*)(ws + off); off += 2654208ull;
  unsigned short* wtf1  = (unsigned short*)(ws + off); off += 10616832ull;
  unsigned short* wtf2  = (unsigned short*)(ws + off); off += 10616832ull;
  float*          adab  = (float*)(ws + off); off += 884736ull;

  const dim3 tb(32, 8);
  hipLaunchKernelGGL(wtrans_kernel, dim3(QKVN / 32, DD / 32), tb, 0, stream, qkv_w, wtq, DD, QKVN);
  hipLaunchKernelGGL(wtrans_kernel, dim3(DD / 32, DD / 32),   tb, 0, stream, proj_w, wtp, DD, DD);
  hipLaunchKernelGGL(wtrans_kernel, dim3(MLPD / 32, DD / 32), tb, 0, stream, fc1_w, wtf1, DD, MLPD);
  hipLaunchKernelGGL(wtrans_kernel, dim3(DD / 32, MLPD / 32), tb, 0, stream, fc2_w, wtf2, MLPD, DD);

  hipLaunchKernelGGL(ada_kernel, dim3(ADAN / 256, 32), dim3(256), 0, stream, c, ada_w, ada_b, adab);

  hipLaunchKernelGGL(ln_mod_kernel, dim3(MROWS), dim3(256), 0, stream, x, adab, 0, xm);

  hipLaunchKernelGGL((gemm256<0>), dim3(128 * 27), dim3(256), 0, stream,
                     xm, wtq, qkv_b, nullptr, 0, nullptr, qkvbuf, nullptr, QKVN, DD, 27);

  hipLaunchKernelGGL(attn_kernel, dim3(MROWS / 4), dim3(256), 0, stream, qkvbuf, attnbuf);

  hipLaunchKernelGGL((gemm256<1>), dim3(128 * 9), dim3(256), 0, stream,
                     attnbuf, wtp, proj_b, adab, 2304, x, nullptr, out, DD, DD, 9);

  hipLaunchKernelGGL(ln_mod_kernel, dim3(MROWS), dim3(256), 0, stream, out, adab, 3456, xm);

  hipLaunchKernelGGL((gemm256<2>), dim3(128 * 36), dim3(256), 0, stream,
                     xm, wtf1, fc1_b, nullptr, 0, nullptr, hbuf, nullptr, MLPD, DD, 36);

  hipLaunchKernelGGL((gemm256<3>), dim3(128 * 9), dim3(256), 0, stream,
                     hbuf, wtf2, fc2_b, adab, 5760, nullptr, nullptr, out, DD, MLPD, 9);
}